// Round 3
// baseline (285.953 us; speedup 1.0000x reference)
//
#include <hip/hip_runtime.h>
#include <hip/hip_bf16.h>

#define M_NODES 50000
#define K_DIM   512
#define N_DIM   128

typedef short s16x8 __attribute__((ext_vector_type(8)));
typedef float f32x4 __attribute__((ext_vector_type(4)));

static __device__ __forceinline__ ushort f2bf(float f) {
  uint u = __float_as_uint(f);
  u += 0x7fff + ((u >> 16) & 1);   // RNE
  return (ushort)(u >> 16);
}

// ---------------- zero-fill d_out (replaces slow hipMemsetAsync) ------------
__global__ __launch_bounds__(256) void zero_out_k(float4* __restrict__ p, int n4) {
  int i = blockIdx.x * 256 + threadIdx.x;
  const int stride = gridDim.x * 256;
  for (; i < n4; i += stride) p[i] = make_float4(0.f, 0.f, 0.f, 0.f);
}

// ---------------- prep: Wt[col][k] = bf16(W[k][col]), [128][512] bf16 -------
__global__ __launch_bounds__(256) void prep_wt(const float* __restrict__ W,
                                               ushort* __restrict__ Wt) {
  int t = blockIdx.x * 256 + threadIdx.x;   // 0..16383
  int k  = t >> 5;                          // 0..511
  int c0 = (t & 31) * 4;                    // 0..124
  float4 v = *reinterpret_cast<const float4*>(&W[(size_t)k * N_DIM + c0]);
  Wt[(size_t)(c0 + 0) * K_DIM + k] = f2bf(v.x);
  Wt[(size_t)(c0 + 1) * K_DIM + k] = f2bf(v.y);
  Wt[(size_t)(c0 + 2) * K_DIM + k] = f2bf(v.z);
  Wt[(size_t)(c0 + 3) * K_DIM + k] = f2bf(v.w);
}

// ---------------- GEMM: S = X @ W via bf16 MFMA, no LDS, reg-pipelined ------
// Block 256 = 4 waves. Wave w: rows bid*32 + (w>>1)*16, cols (w&1)*64.
// Grid 1563 -> 6252 waves (~6.1/SIMD). Explicit 2-deep load pipeline.
// MFMA 16x16x32: A[l&15][(l>>4)*8+j], B[(l>>4)*8+j][l&15], D[(l>>4)*4+r][l&15].

#define LDA(A0, A1, K0) \
  A0 = *reinterpret_cast<const float4*>(xp + (K0)); \
  A1 = *reinterpret_cast<const float4*>(xp + (K0) + 4);

#define LDB(B0, B1, B2, B3, K0) \
  B0 = *reinterpret_cast<const s16x8*>(bp0 + (K0)); \
  B1 = *reinterpret_cast<const s16x8*>(bp1 + (K0)); \
  B2 = *reinterpret_cast<const s16x8*>(bp2 + (K0)); \
  B3 = *reinterpret_cast<const s16x8*>(bp3 + (K0));

#define CVTA(A0, A1, AF) \
  AF[0] = (short)f2bf(A0.x); AF[1] = (short)f2bf(A0.y); \
  AF[2] = (short)f2bf(A0.z); AF[3] = (short)f2bf(A0.w); \
  AF[4] = (short)f2bf(A1.x); AF[5] = (short)f2bf(A1.y); \
  AF[6] = (short)f2bf(A1.z); AF[7] = (short)f2bf(A1.w);

#define MFMA4(AF, B0, B1, B2, B3) \
  acc0 = __builtin_amdgcn_mfma_f32_16x16x32_bf16(AF, B0, acc0, 0, 0, 0); \
  acc1 = __builtin_amdgcn_mfma_f32_16x16x32_bf16(AF, B1, acc1, 0, 0, 0); \
  acc2 = __builtin_amdgcn_mfma_f32_16x16x32_bf16(AF, B2, acc2, 0, 0, 0); \
  acc3 = __builtin_amdgcn_mfma_f32_16x16x32_bf16(AF, B3, acc3, 0, 0, 0);

__global__ __launch_bounds__(256, 4) void gemm_mfma(const float* __restrict__ X,
                                                    const ushort* __restrict__ Wt,
                                                    float* __restrict__ S) {
  const int tid = threadIdx.x;
  const int wid = tid >> 6;
  const int l   = tid & 63;
  const int l15 = l & 15;
  const int lg  = l >> 4;                    // 0..3
  const int r0  = blockIdx.x * 32 + (wid >> 1) * 16;
  const int c0  = (wid & 1) * 64;

  int arow = r0 + l15;
  if (arow >= M_NODES) arow = M_NODES - 1;   // clamp: garbage only lands in
                                             // D rows >= M, never stored
  const float*  xp  = X  + (size_t)arow * K_DIM + lg * 8;
  const ushort* bp0 = Wt + (size_t)(c0 + l15) * K_DIM + lg * 8;
  const ushort* bp1 = bp0 + 16 * K_DIM;
  const ushort* bp2 = bp0 + 32 * K_DIM;
  const ushort* bp3 = bp0 + 48 * K_DIM;

  f32x4 acc0 = {0.f,0.f,0.f,0.f}, acc1 = {0.f,0.f,0.f,0.f};
  f32x4 acc2 = {0.f,0.f,0.f,0.f}, acc3 = {0.f,0.f,0.f,0.f};

  float4 a0c, a1c, a0n, a1n;
  s16x8 b0c, b1c, b2c, b3c, b0n, b1n, b2n, b3n;

  LDA(a0c, a1c, 0) LDB(b0c, b1c, b2c, b3c, 0)
#pragma unroll
  for (int ks = 0; ks < 16; ks += 2) {
    if (ks + 1 < 16) { LDA(a0n, a1n, (ks + 1) * 32) LDB(b0n, b1n, b2n, b3n, (ks + 1) * 32) }
    { s16x8 af; CVTA(a0c, a1c, af) MFMA4(af, b0c, b1c, b2c, b3c) }
    if (ks + 2 < 16) { LDA(a0c, a1c, (ks + 2) * 32) LDB(b0c, b1c, b2c, b3c, (ks + 2) * 32) }
    { s16x8 af; CVTA(a0n, a1n, af) MFMA4(af, b0n, b1n, b2n, b3n) }
  }

#pragma unroll
  for (int r = 0; r < 4; ++r) {
    const int row = r0 + lg * 4 + r;
    if (row < M_NODES) {
      float* sp = S + (size_t)row * N_DIM + c0 + l15;
      sp[0]  = acc0[r];
      sp[16] = acc1[r];
      sp[32] = acc2[r];
      sp[48] = acc3[r];
    }
  }
}

// ---------------- SpMM: out = segment_sum(S[src]*val, dst), dst sorted ------
// EPB=256 (3125 blocks), 128 thr = 1 col each. 32-deep batches, 2-stage pipe.
#define EPB 256
#define SBATCH 32
#define NB (EPB / SBATCH)

#define SLOAD(BUF, B) \
  _Pragma("unroll") for (int j = 0; j < SBATCH; ++j) \
    BUF[j] = S[(size_t)s_src[(B) * SBATCH + j] * N_DIM + c];

#define SPROC(BUF, B) \
  _Pragma("unroll") for (int j = 0; j < SBATCH; ++j) { \
    int d = s_dst[(B) * SBATCH + j]; \
    if (d != cur) { atomicAdd(&out[(size_t)cur * N_DIM + c], acc); acc = 0.f; cur = d; } \
    acc += s_val[(B) * SBATCH + j] * BUF[j]; }

__global__ __launch_bounds__(128, 4) void spmm_edges(const float* __restrict__ S,
                                                     const int* __restrict__ esrc,
                                                     const int* __restrict__ edst,
                                                     const float* __restrict__ eval,
                                                     float* __restrict__ out) {
  __shared__ int   s_src[EPB];
  __shared__ int   s_dst[EPB];
  __shared__ float s_val[EPB];

  const int e0  = blockIdx.x * EPB;
  const int tid = threadIdx.x;

#pragma unroll
  for (int i = 0; i < EPB / 128; ++i) {
    int idx = tid + i * 128;
    s_src[idx] = esrc[e0 + idx];
    s_dst[idx] = edst[e0 + idx];
    s_val[idx] = eval[e0 + idx];
  }
  __syncthreads();

  const int c = tid;               // output column 0..127
  float acc = 0.f;
  int   cur = s_dst[0];

  float va[SBATCH], vb[SBATCH];

  SLOAD(va, 0)
#pragma unroll
  for (int b = 0; b < NB; b += 2) {
    if (b + 1 < NB) { SLOAD(vb, b + 1) }
    SPROC(va, b)
    if (b + 2 < NB) { SLOAD(va, b + 2) }
    SPROC(vb, b + 1)
  }
  atomicAdd(&out[(size_t)cur * N_DIM + c], acc);
}

// ---------------- launch ----------------
extern "C" void kernel_launch(void* const* d_in, const int* in_sizes, int n_in,
                              void* d_out, int out_size, void* d_ws, size_t ws_size,
                              hipStream_t stream) {
  const float* x        = (const float*)d_in[0];
  const int*   edge_src = (const int*)d_in[1];
  const int*   edge_dst = (const int*)d_in[2];
  const float* edge_val = (const float*)d_in[3];
  const float* weight   = (const float*)d_in[4];
  float*       out      = (float*)d_out;

  float*  support = (float*)d_ws;                                        // 25.6 MB
  ushort* wt      = (ushort*)((char*)d_ws + (size_t)M_NODES * N_DIM * 4);// 128 KB

  const int n_edges = in_sizes[1];

  zero_out_k<<<dim3(2048), dim3(256), 0, stream>>>((float4*)d_out, out_size / 4);

  prep_wt<<<dim3(64), dim3(256), 0, stream>>>(weight, wt);

  gemm_mfma<<<dim3((M_NODES + 31) / 32), dim3(256), 0, stream>>>(x, wt, support);

  spmm_edges<<<dim3(n_edges / EPB), dim3(128), 0, stream>>>(support, edge_src,
                                                            edge_dst, edge_val, out);
}

// Round 5
// 241.405 us; speedup vs baseline: 1.1845x; 1.1845x over previous
//
#include <hip/hip_runtime.h>
#include <hip/hip_bf16.h>

#define M_NODES 50000
#define K_DIM   512
#define N_DIM   128

typedef short s16x8 __attribute__((ext_vector_type(8)));
typedef float f32x4 __attribute__((ext_vector_type(4)));

static __device__ __forceinline__ ushort f2bf(float f) {
  uint u = __float_as_uint(f);
  u += 0x7fff + ((u >> 16) & 1);   // RNE
  return (ushort)(u >> 16);
}

static __device__ __forceinline__ uint cvtpk(float lo, float hi) {
  uint r;
  asm("v_cvt_pk_bf16_f32 %0, %1, %2" : "=v"(r) : "v"(lo), "v"(hi));
  return r;
}

// async global->LDS, 16B per lane. LDS dest must be wave-uniform base (HW adds lane*16).
static __device__ __forceinline__ void g2l16(const void* g, void* l) {
  __builtin_amdgcn_global_load_lds((const __attribute__((address_space(1))) void*)g,
                                   (__attribute__((address_space(3))) void*)l, 16, 0, 0);
}

// ---------------- prep: zero d_out + Wt[col][k] = bf16(W[k][col]) -----------
__global__ __launch_bounds__(256) void prep_zero(const float* __restrict__ W,
                                                 ushort* __restrict__ Wt,
                                                 float4* __restrict__ o4, int n4) {
  const int t = blockIdx.x * 256 + threadIdx.x;
  const int stride = gridDim.x * 256;
  for (int i = t; i < n4; i += stride) o4[i] = make_float4(0.f, 0.f, 0.f, 0.f);
  if (t < 16384) {
    int k  = t >> 5;
    int c0 = (t & 31) * 4;
    float4 v = *reinterpret_cast<const float4*>(&W[(size_t)k * N_DIM + c0]);
    Wt[(size_t)(c0 + 0) * K_DIM + k] = f2bf(v.x);
    Wt[(size_t)(c0 + 1) * K_DIM + k] = f2bf(v.y);
    Wt[(size_t)(c0 + 2) * K_DIM + k] = f2bf(v.z);
    Wt[(size_t)(c0 + 3) * K_DIM + k] = f2bf(v.w);
  }
}

// ---------------- GEMM: S = X @ W, m97-style global_load_lds pipeline -------
// 128x128 tile, BK=32, 256 thr = 4 waves (2x2). Wave: 64x64 = 4x4 16x16 frags.
// A LDS [128 rows][8 chunks of 4 fp32], chunk XOR-swizzled by row&7 (source
// pre-swizzled so LDS dest stays linear). B LDS [128 cols][32 k] bf16, linear.
#define GBK 32
#define NKS (K_DIM / GBK)   // 16

__global__ __launch_bounds__(256, 2) void gemm_mfma(const float* __restrict__ X,
                                                    const ushort* __restrict__ Wt,
                                                    float* __restrict__ S) {
  __shared__ float  Albs[2][128 * 32];   // 16 KB each
  __shared__ ushort Blbs[2][128 * 32];   // 8 KB each

  const int tid = threadIdx.x;
  const int w   = tid >> 6;
  const int l   = tid & 63;
  const int l15 = l & 15, lg = l >> 4;
  const int wr  = w >> 1, wc = w & 1;
  const int row0 = blockIdx.x * 128;

  // staging source pointers (per-lane, pre-swizzled for A)
  const float* aSrc[4];
#pragma unroll
  for (int i = 0; i < 4; ++i) {
    int q = i * 256 + w * 64 + l;        // chunk 0..1023
    int r = q >> 3;
    int c = (q & 7) ^ (r & 7);           // inverse swizzle on source
    int rg = row0 + r; if (rg >= M_NODES) rg = M_NODES - 1;
    aSrc[i] = X + (size_t)rg * K_DIM + c * 4;
  }
  const ushort* bSrc[2];
#pragma unroll
  for (int i = 0; i < 2; ++i) {
    int q = i * 256 + w * 64 + l;        // chunk 0..511
    int col = q >> 2, j = q & 3;
    bSrc[i] = Wt + (size_t)col * K_DIM + j * 8;
  }

  f32x4 acc[4][4];
#pragma unroll
  for (int am = 0; am < 4; ++am)
#pragma unroll
    for (int bn = 0; bn < 4; ++bn) acc[am][bn] = (f32x4){0.f, 0.f, 0.f, 0.f};

#define STAGE(buf, kk) { \
  _Pragma("unroll") for (int i = 0; i < 4; ++i) \
    g2l16(aSrc[i] + (kk), (char*)&Albs[buf][0] + (size_t)(i * 256 + w * 64) * 16); \
  _Pragma("unroll") for (int i = 0; i < 2; ++i) \
    g2l16(bSrc[i] + (kk), (char*)&Blbs[buf][0] + (size_t)(i * 256 + w * 64) * 16); }

#define COMPUTE(buf) { \
  s16x8 af[4], bfr[4]; \
  _Pragma("unroll") for (int am = 0; am < 4; ++am) { \
    const int r = wr * 64 + am * 16 + l15; \
    const int s = r & 7; \
    float4 f0 = *reinterpret_cast<const float4*>(&Albs[buf][(r * 8 + ((lg * 2) ^ s)) * 4]); \
    float4 f1 = *reinterpret_cast<const float4*>(&Albs[buf][(r * 8 + ((lg * 2 + 1) ^ s)) * 4]); \
    union { s16x8 v; uint u[4]; } a; \
    a.u[0] = cvtpk(f0.x, f0.y); a.u[1] = cvtpk(f0.z, f0.w); \
    a.u[2] = cvtpk(f1.x, f1.y); a.u[3] = cvtpk(f1.z, f1.w); \
    af[am] = a.v; } \
  _Pragma("unroll") for (int bn = 0; bn < 4; ++bn) { \
    const int c = wc * 64 + bn * 16 + l15; \
    bfr[bn] = *reinterpret_cast<const s16x8*>(&Blbs[buf][c * 32 + lg * 8]); } \
  _Pragma("unroll") for (int am = 0; am < 4; ++am) \
    _Pragma("unroll") for (int bn = 0; bn < 4; ++bn) \
      acc[am][bn] = __builtin_amdgcn_mfma_f32_16x16x32_bf16(af[am], bfr[bn], acc[am][bn], 0, 0, 0); }

  STAGE(0, 0)
  __syncthreads();
#pragma unroll
  for (int t = 0; t < NKS; ++t) {
    if (t + 1 < NKS) STAGE((t + 1) & 1, (t + 1) * GBK)
    COMPUTE(t & 1)
    __syncthreads();
  }
#undef STAGE
#undef COMPUTE

#pragma unroll
  for (int am = 0; am < 4; ++am) {
#pragma unroll
    for (int rr = 0; rr < 4; ++rr) {
      const int row = row0 + wr * 64 + am * 16 + lg * 4 + rr;
      if (row < M_NODES) {
        float* sp = S + (size_t)row * N_DIM + wc * 64 + l15;
#pragma unroll
        for (int bn = 0; bn < 4; ++bn)
          sp[bn * 16] = acc[am][bn][rr];
      }
    }
  }
}

// ---------------- SpMM: out = segment_sum(S[src]*val, dst), dst sorted ------
// EPB=256 (3125 blocks), 128 thr = 1 col each. 32-deep batches, 2-stage pipe.
// Interior runs (dst fully inside block) use plain stores; boundary runs atomic.
#define EPB 256
#define SBATCH 32
#define NB (EPB / SBATCH)

#define SLOAD(BUF, B) \
  _Pragma("unroll") for (int j = 0; j < SBATCH; ++j) \
    BUF[j] = S[(size_t)s_src[(B) * SBATCH + j] * N_DIM + c];

#define SPROC(BUF, B) \
  _Pragma("unroll") for (int j = 0; j < SBATCH; ++j) { \
    int d = s_dst[(B) * SBATCH + j]; \
    if (d != cur) { \
      if (cur == first) atomicAdd(&out[(size_t)cur * N_DIM + c], acc); \
      else out[(size_t)cur * N_DIM + c] = acc; \
      acc = 0.f; cur = d; \
    } \
    acc += s_val[(B) * SBATCH + j] * BUF[j]; }

__global__ __launch_bounds__(128) void spmm_edges(const float* __restrict__ S,
                                                  const int* __restrict__ esrc,
                                                  const int* __restrict__ edst,
                                                  const float* __restrict__ eval,
                                                  float* __restrict__ out) {
  __shared__ int   s_src[EPB];
  __shared__ int   s_dst[EPB];
  __shared__ float s_val[EPB];

  const int e0  = blockIdx.x * EPB;
  const int tid = threadIdx.x;

#pragma unroll
  for (int i = 0; i < EPB / 128; ++i) {
    int idx = tid + i * 128;
    s_src[idx] = esrc[e0 + idx];
    s_dst[idx] = edst[e0 + idx];
    s_val[idx] = eval[e0 + idx];
  }
  __syncthreads();

  const int c = tid;               // output column 0..127
  const int first = s_dst[0];
  float acc = 0.f;
  int   cur = first;

  float va[SBATCH], vb[SBATCH];

  SLOAD(va, 0)
#pragma unroll
  for (int b = 0; b < NB; b += 2) {
    if (b + 1 < NB) { SLOAD(vb, b + 1) }
    SPROC(va, b)
    if (b + 2 < NB) { SLOAD(va, b + 2) }
    SPROC(vb, b + 1)
  }
  atomicAdd(&out[(size_t)cur * N_DIM + c], acc);   // last run may span blocks
}

// ---------------- launch ----------------
extern "C" void kernel_launch(void* const* d_in, const int* in_sizes, int n_in,
                              void* d_out, int out_size, void* d_ws, size_t ws_size,
                              hipStream_t stream) {
  const float* x        = (const float*)d_in[0];
  const int*   edge_src = (const int*)d_in[1];
  const int*   edge_dst = (const int*)d_in[2];
  const float* edge_val = (const float*)d_in[3];
  const float* weight   = (const float*)d_in[4];
  float*       out      = (float*)d_out;

  float*  support = (float*)d_ws;                                        // 25.6 MB
  ushort* wt      = (ushort*)((char*)d_ws + (size_t)M_NODES * N_DIM * 4);// 128 KB

  const int n_edges = in_sizes[1];

  prep_zero<<<dim3(512), dim3(256), 0, stream>>>(weight, wt, (float4*)d_out,
                                                 out_size / 4);

  gemm_mfma<<<dim3((M_NODES + 127) / 128), dim3(256), 0, stream>>>(x, wt, support);

  spmm_edges<<<dim3(n_edges / EPB), dim3(128), 0, stream>>>(support, edge_src,
                                                            edge_dst, edge_val, out);
}